// Round 4
// baseline (705.779 us; speedup 1.0000x reference)
//
#include <hip/hip_runtime.h>
#include <stdint.h>

// Problem constants
#define M_TOTAL 65536       // B*S = 16*4096
#define DIM     1024        // D = K
#define NQKV    3072        // Q|K|V concatenated output cols
#define NHEAD   16
#define HDIM    64

typedef __attribute__((ext_vector_type(8))) _Float16 f16x8;
typedef __attribute__((ext_vector_type(4))) _Float16 f16x4;
typedef __attribute__((ext_vector_type(4))) float    f32x4;

// ---------------------------------------------------------------- prep: x -> f16
__global__ __launch_bounds__(256) void cvt_x_kernel(const float* __restrict__ x,
                                                    _Float16* __restrict__ xh,
                                                    int n4) {
    int i = blockIdx.x * blockDim.x + threadIdx.x;
    int stride = gridDim.x * blockDim.x;
    const float4* x4 = (const float4*)x;
    f16x4* o4 = (f16x4*)xh;
    for (; i < n4; i += stride) {
        float4 v = x4[i];
        f16x4 o;
        o[0] = (_Float16)v.x; o[1] = (_Float16)v.y;
        o[2] = (_Float16)v.z; o[3] = (_Float16)v.w;
        o4[i] = o;
    }
}

// ---------------------------------------------- prep: W (K x N) -> Wt f16 (N x K), 3 mats
__global__ void cvt_w_kernel(const float* __restrict__ Wq,
                             const float* __restrict__ Wk,
                             const float* __restrict__ Wv,
                             _Float16* __restrict__ Wt) {
    __shared__ float tile[32][33];
    int which = blockIdx.z;
    const float* W = (which == 0) ? Wq : (which == 1) ? Wk : Wv;
    int d0 = blockIdx.y * 32, n0 = blockIdx.x * 32;
    int tx = threadIdx.x, ty = threadIdx.y;
    tile[ty][tx] = W[(size_t)(d0 + ty) * DIM + n0 + tx];
    __syncthreads();
    Wt[(size_t)(which * DIM + n0 + ty) * DIM + d0 + tx] = (_Float16)tile[tx][ty];
}

// ---------------------------------------------------------------- prep: bias concat
__global__ __launch_bounds__(256) void bias_kernel(const float* __restrict__ bq,
                                                   const float* __restrict__ bk,
                                                   const float* __restrict__ bv,
                                                   float* __restrict__ bias) {
    int i = blockIdx.x * 256 + threadIdx.x;
    if (i < NQKV)
        bias[i] = (i < 1024) ? bq[i] : (i < 2048) ? bk[i - 1024] : bv[i - 2048];
}

// ---------------------------------------------------------------- fused QKV GEMM
// PERSISTENT version: grid = 256 blocks (1/CU, M-panel each), each block loops
// over 12 n-tiles = 192 continuous K-steps through the 8-phase pipeline.
// 256x256 tile, BK=64, 8 waves (2M x 4N); per phase {ds_read subtile || 1
// half-tile global_load_lds -> barrier -> setprio -> 16 MFMA -> setprio ->
// barrier}; counted vmcnt(4) at phases 3/7 (never 0 in the stream).
// LDS 128 KiB: A[2][256][64] + B[2][256][64] f16, XOR-swizzle slot^=(row&7),
// inverse swizzle pre-applied to the global source (gload_lds writes linearly).

#define LDSA(slot)  ((slot) << 15)
#define LDSB(slot)  (65536 + ((slot) << 15))

#define MFMA_Q(MIBASE, NIBASE)                                                  \
    __builtin_amdgcn_s_setprio(1);                                              \
    _Pragma("unroll") for (int mi = 0; mi < 4; ++mi)                            \
    _Pragma("unroll") for (int ni = 0; ni < 2; ++ni)                            \
    _Pragma("unroll") for (int ks = 0; ks < 2; ++ks)                            \
        acc[(MIBASE) + mi][(NIBASE) + ni] = __builtin_amdgcn_mfma_f32_16x16x32_f16( \
            a[mi][ks], b[(NIBASE) + ni][ks], acc[(MIBASE) + mi][(NIBASE) + ni], 0, 0, 0); \
    __builtin_amdgcn_s_setprio(0);

__global__ __launch_bounds__(512, 2) void qkv_gemm_kernel(const _Float16* __restrict__ Xh,
                                                          const _Float16* __restrict__ Wth,
                                                          const float* __restrict__ bias,
                                                          _Float16* __restrict__ Ch) {
    extern __shared__ char smem[];

    const int bid  = blockIdx.x;                 // 256 blocks = 256 M-panels
    const int brow = bid * 256;

    const int tid = threadIdx.x;
    const int w   = tid >> 6;          // wave 0..7
    const int l   = tid & 63;
    const int wm  = w >> 2;            // 0..1 -> rows wm*128..+127
    const int wn  = w & 3;             // 0..3 -> cols wn*64..+63

    // ---- staging source (inverse-swizzled): thread covers row (w*8 + l>>3), slot (l&7)^(l>>3)
    const int lrow8 = l >> 3;
    const int lcol8 = (l & 7) ^ lrow8;
    const _Float16* pAsrc = Xh  + (size_t)(brow + w * 8 + lrow8) * DIM + lcol8 * 8;
    const _Float16* pBsrc = Wth + (size_t)(w * 8 + lrow8) * DIM + lcol8 * 8;

    // one half-tile = 128 rows x 64 cols = 16 KiB = 2 gload issues.
    // s = global K-step (0..191): A uses k = (s&15)*64; B adds n-panel (s>>4)*256 rows.
    // s is clamped by callers to 191 (over-stage writes junk into dead slots — safe).
    auto stA = [&](int slot, int s, int half) {
        if (s > 191) s = 191;
        const _Float16* sp = pAsrc + ((size_t)half << 17) + ((size_t)(s & 15) << 6);
        char* d = smem + LDSA(slot) + (half << 14) + (w << 10);
        __builtin_amdgcn_global_load_lds((const __attribute__((address_space(1))) void*)sp,
                                         (__attribute__((address_space(3))) void*)d, 16, 0, 0);
        __builtin_amdgcn_global_load_lds((const __attribute__((address_space(1))) void*)(sp + (1 << 16)),
                                         (__attribute__((address_space(3))) void*)(d + 8192), 16, 0, 0);
    };
    auto stB = [&](int slot, int s, int half) {
        if (s > 191) s = 191;
        const _Float16* sp = pBsrc + ((size_t)(s >> 4) << 18) + ((size_t)half << 17) + ((size_t)(s & 15) << 6);
        char* d = smem + LDSB(slot) + (half << 14) + (w << 10);
        __builtin_amdgcn_global_load_lds((const __attribute__((address_space(1))) void*)sp,
                                         (__attribute__((address_space(3))) void*)d, 16, 0, 0);
        __builtin_amdgcn_global_load_lds((const __attribute__((address_space(1))) void*)(sp + (1 << 16)),
                                         (__attribute__((address_space(3))) void*)(d + 8192), 16, 0, 0);
    };

    // ---- swizzled LDS reads: physical 16B slot = logical slot ^ (row & 7)
    const int aRowB = ((wm << 7) + (l & 15)) << 7;            // row * 128 B
    const int bRowB = 65536 + (((wn << 6) + (l & 15)) << 7);
    const int xk0 = (((l >> 4) ^ (l & 7)) << 4);
    const int xk1 = ((((l >> 4) + 4) ^ (l & 7)) << 4);
    auto LDA = [&](int slot, int mi, int ks) -> f16x8 {
        return *(const f16x8*)(smem + (slot << 15) + aRowB + (mi << 11) + (ks ? xk1 : xk0));
    };
    auto LDB = [&](int slot, int ni, int ks) -> f16x8 {
        return *(const f16x8*)(smem + (slot << 15) + bRowB + (ni << 11) + (ks ? xk1 : xk0));
    };

    f32x4 acc[8][4] = {};
    f16x8 a[4][2], b[4][2];

    // ================= prologue: B(0), A(0), B(1); wait for B(0),A(0) (leave B(1) in flight)
    stB(0, 0, 0); stB(0, 0, 1);
    stA(0, 0, 0); stA(0, 0, 1);
    stB(1, 1, 0); stB(1, 1, 1);
    asm volatile("s_waitcnt vmcnt(2)" ::: "memory");
    __builtin_amdgcn_s_barrier();
    __builtin_amdgcn_sched_barrier(0);

    // ================= persistent loop: 12 n-tiles x 8 iterations (2 K-tiles each)
#pragma unroll 1
    for (int t = 0; t < 12; ++t) {
#pragma unroll 1
        for (int ii = 0; ii < 8; ++ii) {
            const int u = (t << 4) + (ii << 1);
            // ---- PH0 (K-step u, slot0, m0-3 x n0-1) | stage A(u+1) -> slot1
#pragma unroll
            for (int mi = 0; mi < 4; ++mi) { a[mi][0] = LDA(0, mi, 0); a[mi][1] = LDA(0, mi, 1); }
#pragma unroll
            for (int ni = 0; ni < 2; ++ni) { b[ni][0] = LDB(0, ni, 0); b[ni][1] = LDB(0, ni, 1); }
            stA(1, u + 1, 0);
            __builtin_amdgcn_s_barrier();
            MFMA_Q(0, 0)
            __builtin_amdgcn_s_barrier();
            // ---- PH1 (m0-3 x n2-3) | stage A(u+1) h1
            b[2][0] = LDB(0, 2, 0); b[2][1] = LDB(0, 2, 1);
            b[3][0] = LDB(0, 3, 0); b[3][1] = LDB(0, 3, 1);
            stA(1, u + 1, 1);
            __builtin_amdgcn_s_barrier();
            MFMA_Q(0, 2)
            __builtin_amdgcn_s_barrier();
            // ---- PH2 (m4-7 x n0-1) | stage B(u+2) h0 -> slot0
#pragma unroll
            for (int mi = 0; mi < 4; ++mi) { a[mi][0] = LDA(0, mi + 4, 0); a[mi][1] = LDA(0, mi + 4, 1); }
            stB(0, u + 2, 0);
            __builtin_amdgcn_s_barrier();
            MFMA_Q(4, 0)
            __builtin_amdgcn_s_barrier();
            // ---- PH3 (m4-7 x n2-3) | stage B(u+2) h1; publish A(u+1),B(u+1)
            stB(0, u + 2, 1);
            asm volatile("s_waitcnt vmcnt(4)" ::: "memory");
            __builtin_amdgcn_s_barrier();
            __builtin_amdgcn_sched_barrier(0);
            MFMA_Q(4, 2)
            __builtin_amdgcn_s_barrier();
            // ---- PH4 (K-step u+1, slot1, m0-3 x n0-1) | stage A(u+2) -> slot0
#pragma unroll
            for (int mi = 0; mi < 4; ++mi) { a[mi][0] = LDA(1, mi, 0); a[mi][1] = LDA(1, mi, 1); }
#pragma unroll
            for (int ni = 0; ni < 2; ++ni) { b[ni][0] = LDB(1, ni, 0); b[ni][1] = LDB(1, ni, 1); }
            stA(0, u + 2, 0);
            __builtin_amdgcn_s_barrier();
            MFMA_Q(0, 0)
            __builtin_amdgcn_s_barrier();
            // ---- PH5 (m0-3 x n2-3) | stage A(u+2) h1
            b[2][0] = LDB(1, 2, 0); b[2][1] = LDB(1, 2, 1);
            b[3][0] = LDB(1, 3, 0); b[3][1] = LDB(1, 3, 1);
            stA(0, u + 2, 1);
            __builtin_amdgcn_s_barrier();
            MFMA_Q(0, 2)
            __builtin_amdgcn_s_barrier();
            // ---- PH6 (m4-7 x n0-1) | stage B(u+3) h0 -> slot1
#pragma unroll
            for (int mi = 0; mi < 4; ++mi) { a[mi][0] = LDA(1, mi + 4, 0); a[mi][1] = LDA(1, mi + 4, 1); }
            stB(1, u + 3, 0);
            __builtin_amdgcn_s_barrier();
            MFMA_Q(4, 0)
            __builtin_amdgcn_s_barrier();
            // ---- PH7 (m4-7 x n2-3) | stage B(u+3) h1; publish A(u+2),B(u+2)
            stB(1, u + 3, 1);
            asm volatile("s_waitcnt vmcnt(4)" ::: "memory");
            __builtin_amdgcn_s_barrier();
            __builtin_amdgcn_sched_barrier(0);
            MFMA_Q(4, 2)
            __builtin_amdgcn_s_barrier();
        }

        // ---- tile epilogue (no waitcnt, no LDS): + bias -> f16 stores, zero acc.
        // C/D layout: col = l&15, row = (l>>4)*4 + jj
        {
            const int bcol = t << 8;
            const int r4 = (l >> 4) << 2;
#pragma unroll
            for (int ni = 0; ni < 4; ++ni) {
                const int col = bcol + (wn << 6) + (ni << 4) + (l & 15);
                const float bv = bias[col];
#pragma unroll
                for (int mi = 0; mi < 8; ++mi) {
#pragma unroll
                    for (int jj = 0; jj < 4; ++jj) {
                        const int row = brow + (wm << 7) + (mi << 4) + r4 + jj;
                        Ch[(size_t)row * NQKV + col] = (_Float16)(acc[mi][ni][jj] + bv);
                    }
                }
            }
#pragma unroll
            for (int mi = 0; mi < 8; ++mi)
#pragma unroll
                for (int ni = 0; ni < 4; ++ni)
                    acc[mi][ni] = (f32x4){0.f, 0.f, 0.f, 0.f};
        }
    }

    // drain the trailing (junk) prefetches before kernel end
    asm volatile("s_waitcnt vmcnt(0)" ::: "memory");
}

// ---------------------------------------------------------------- per-position attention
__global__ __launch_bounds__(256) void attn_kernel(const _Float16* __restrict__ QKVh,
                                                   float* __restrict__ out) {
    __shared__ _Float16 vlds[4][1024];
    __shared__ float attlds[4][16][16];

    const int w = threadIdx.x >> 6, l = threadIdx.x & 63;
    const size_t p = (size_t)blockIdx.x * 4 + w;
    const _Float16* base = QKVh + p * NQKV;
    const _Float16* qrow = base;
    const _Float16* krow = base + 1024;
    const _Float16* vrow = base + 2048;
    const int h = l & 15;
    const int g4 = (l >> 4) * 4;

    *(uint4*)&vlds[w][l * 16]     = *(const uint4*)&vrow[l * 16];
    *(uint4*)&vlds[w][l * 16 + 8] = *(const uint4*)&vrow[l * 16 + 8];

    const int fo = (l & 15) * HDIM + (l >> 4) * 8;
    f16x8 aK0 = *(const f16x8*)&krow[fo];
    f16x8 aK1 = *(const f16x8*)&krow[fo + 32];
    f16x8 bQ0 = *(const f16x8*)&qrow[fo];
    f16x8 bQ1 = *(const f16x8*)&qrow[fo + 32];

    f32x4 sT = {0.f, 0.f, 0.f, 0.f};
    sT = __builtin_amdgcn_mfma_f32_16x16x32_f16(aK0, bQ0, sT, 0, 0, 0);
    sT = __builtin_amdgcn_mfma_f32_16x16x32_f16(aK1, bQ1, sT, 0, 0, 0);
    // lane holds s[h = l&15][g = g4 + i] = sT[i]

    float m = fmaxf(fmaxf(sT[0], sT[1]), fmaxf(sT[2], sT[3]));
    m = fmaxf(m, __shfl_xor(m, 16));
    m = fmaxf(m, __shfl_xor(m, 32));
    float e0 = __expf(sT[0] - m), e1 = __expf(sT[1] - m);
    float e2 = __expf(sT[2] - m), e3 = __expf(sT[3] - m);
    float s = e0 + e1 + e2 + e3;
    s += __shfl_xor(s, 16);
    s += __shfl_xor(s, 32);
    const float inv = 1.0f / s;

    float4 att = make_float4(e0 * inv, e1 * inv, e2 * inv, e3 * inv);
    *(float4*)&attlds[w][h][g4] = att;
    __syncthreads();

    const int dbase = (l >> 4) * 16;
    float acc[16];
#pragma unroll
    for (int c = 0; c < 16; ++c) acc[c] = 0.f;

#pragma unroll
    for (int g = 0; g < 16; ++g) {
        const float av = attlds[w][h][g];
        f16x8 v0 = *(const f16x8*)&vlds[w][g * HDIM + dbase];
        f16x8 v1 = *(const f16x8*)&vlds[w][g * HDIM + dbase + 8];
#pragma unroll
        for (int c = 0; c < 8; ++c) {
            acc[c]     += av * (float)v0[c];
            acc[c + 8] += av * (float)v1[c];
        }
    }

    float* op = out + p * DIM + h * HDIM + dbase;
#pragma unroll
    for (int c = 0; c < 16; c += 4)
        *(float4*)(op + c) = make_float4(acc[c], acc[c + 1], acc[c + 2], acc[c + 3]);
}

// ---------------------------------------------------------------- launch
extern "C" void kernel_launch(void* const* d_in, const int* in_sizes, int n_in,
                              void* d_out, int out_size, void* d_ws, size_t ws_size,
                              hipStream_t stream) {
    const float* x  = (const float*)d_in[0];
    const float* Wq = (const float*)d_in[1];
    const float* bq = (const float*)d_in[2];
    const float* Wk = (const float*)d_in[3];
    const float* bk = (const float*)d_in[4];
    const float* Wv = (const float*)d_in[5];
    const float* bv = (const float*)d_in[6];
    float* out = (float*)d_out;

    char* ws = (char*)d_ws;
    _Float16* Xh  = (_Float16*)ws;
    _Float16* Wth = (_Float16*)(ws + 134217728);
    float*    bias = (float*)(ws + 134217728 + 6291456);
    _Float16* Ch  = (_Float16*)(ws + 134217728 + 6291456 + 12288);

    // allow 128 KiB dynamic LDS (gfx950 has 160 KiB/CU)
    (void)hipFuncSetAttribute((const void*)qkv_gemm_kernel,
                              hipFuncAttributeMaxDynamicSharedMemorySize, 131072);

    hipLaunchKernelGGL(cvt_x_kernel, dim3(2048), dim3(256), 0, stream,
                       x, Xh, (M_TOTAL * DIM) / 4);
    hipLaunchKernelGGL(cvt_w_kernel, dim3(32, 32, 3), dim3(32, 32), 0, stream,
                       Wq, Wk, Wv, Wth);
    hipLaunchKernelGGL(bias_kernel, dim3(12), dim3(256), 0, stream,
                       bq, bk, bv, bias);
    hipLaunchKernelGGL(qkv_gemm_kernel, dim3(M_TOTAL / 256), dim3(512), 131072, stream,
                       Xh, Wth, bias, Ch);
    hipLaunchKernelGGL(attn_kernel, dim3(M_TOTAL / 4), dim3(256), 0, stream,
                       Ch, out);
}

// Round 5
// 615.640 us; speedup vs baseline: 1.1464x; 1.1464x over previous
//
#include <hip/hip_runtime.h>
#include <stdint.h>

// Problem constants
#define M_TOTAL 65536       // B*S = 16*4096
#define DIM     1024        // D = K
#define NQKV    3072        // Q|K|V concatenated output cols
#define NHEAD   16
#define HDIM    64

typedef __attribute__((ext_vector_type(8))) _Float16 f16x8;
typedef __attribute__((ext_vector_type(4))) _Float16 f16x4;
typedef __attribute__((ext_vector_type(4))) float    f32x4;

// ---------------------------------------------------------------- prep: x -> f16
__global__ __launch_bounds__(256) void cvt_x_kernel(const float* __restrict__ x,
                                                    _Float16* __restrict__ xh,
                                                    int n4) {
    int i = blockIdx.x * blockDim.x + threadIdx.x;
    int stride = gridDim.x * blockDim.x;
    const float4* x4 = (const float4*)x;
    f16x4* o4 = (f16x4*)xh;
    for (; i < n4; i += stride) {
        float4 v = x4[i];
        f16x4 o;
        o[0] = (_Float16)v.x; o[1] = (_Float16)v.y;
        o[2] = (_Float16)v.z; o[3] = (_Float16)v.w;
        o4[i] = o;
    }
}

// ---------------------------------------------- prep: W (K x N) -> Wt f16 (N x K), 3 mats
__global__ void cvt_w_kernel(const float* __restrict__ Wq,
                             const float* __restrict__ Wk,
                             const float* __restrict__ Wv,
                             _Float16* __restrict__ Wt) {
    __shared__ float tile[32][33];
    int which = blockIdx.z;
    const float* W = (which == 0) ? Wq : (which == 1) ? Wk : Wv;
    int d0 = blockIdx.y * 32, n0 = blockIdx.x * 32;
    int tx = threadIdx.x, ty = threadIdx.y;
    tile[ty][tx] = W[(size_t)(d0 + ty) * DIM + n0 + tx];
    __syncthreads();
    Wt[(size_t)(which * DIM + n0 + ty) * DIM + d0 + tx] = (_Float16)tile[tx][ty];
}

// ---------------------------------------------------------------- prep: bias concat
__global__ __launch_bounds__(256) void bias_kernel(const float* __restrict__ bq,
                                                   const float* __restrict__ bk,
                                                   const float* __restrict__ bv,
                                                   float* __restrict__ bias) {
    int i = blockIdx.x * 256 + threadIdx.x;
    if (i < NQKV)
        bias[i] = (i < 1024) ? bq[i] : (i < 2048) ? bk[i - 1024] : bv[i - 2048];
}

// ---------------------------------------------------------------- fused QKV GEMM
// Round-3 structure (3072 blocks, 256x256 tile, BK=64, 8 waves, 8-phase,
// counted vmcnt, XOR-swizzled LDS, XCD-aware block swizzle) with:
//  (1) prologue vmcnt(2) (Round-3's vmcnt(4) left A(0) unguaranteed),
//  (2) TRANSPOSED accumulators: mfma(b, a, acc) -> lane holds one m-row and
//      4 contiguous n-cols per fragment,
//  (3) epilogue via LDS bounce: ds_write_b64 fragments (16B-granule XOR
//      swizzle, conflict-free) -> coalesced f16x8 global stores.

#define LDSA(slot)  ((slot) << 15)
#define LDSB(slot)  (65536 + ((slot) << 15))

// 16 MFMAs, operand-swapped: D = b x a  => lane owns m-col = l&15, n-rows (l>>4)*4+j
#define MFMA_Q(MIBASE, NIBASE)                                                  \
    __builtin_amdgcn_s_setprio(1);                                              \
    _Pragma("unroll") for (int mi = 0; mi < 4; ++mi)                            \
    _Pragma("unroll") for (int ni = 0; ni < 2; ++ni)                            \
    _Pragma("unroll") for (int ks = 0; ks < 2; ++ks)                            \
        acc[(MIBASE) + mi][(NIBASE) + ni] = __builtin_amdgcn_mfma_f32_16x16x32_f16( \
            b[(NIBASE) + ni][ks], a[mi][ks], acc[(MIBASE) + mi][(NIBASE) + ni], 0, 0, 0); \
    __builtin_amdgcn_s_setprio(0);

__global__ __launch_bounds__(512, 2) void qkv_gemm_kernel(const _Float16* __restrict__ Xh,
                                                          const _Float16* __restrict__ Wth,
                                                          const float* __restrict__ bias,
                                                          _Float16* __restrict__ Ch) {
    extern __shared__ char smem[];

    // XCD-aware swizzle: 3072 blocks, 3072 % 8 == 0 -> bijective; 12 blocks
    // sharing an A-panel (same tm) land on the same XCD -> A re-reads are L2 hits.
    const int bid = blockIdx.x;
    const int swz = (bid & 7) * (3072 / 8) + (bid >> 3);
    const int tm  = swz / (NQKV / 256);
    const int tn  = swz % (NQKV / 256);
    const int brow = tm * 256;
    const int bcol = tn * 256;

    const int tid = threadIdx.x;
    const int w   = tid >> 6;          // wave 0..7
    const int l   = tid & 63;
    const int wm  = w >> 2;            // 0..1 -> rows wm*128..+127
    const int wn  = w & 3;             // 0..3 -> cols wn*64..+63

    // ---- staging source (inverse-swizzled): thread covers row (w*8 + l>>3), slot (l&7)^(l>>3)
    const int lrow8 = l >> 3;
    const int lcol8 = (l & 7) ^ lrow8;
    const _Float16* pAsrc = Xh  + (size_t)(brow + w * 8 + lrow8) * DIM + lcol8 * 8;
    const _Float16* pBsrc = Wth + (size_t)(bcol + w * 8 + lrow8) * DIM + lcol8 * 8;

    // one half-tile = 128 rows x 64 cols = 16 KiB = 2 gload issues
    auto stA = [&](int slot, int kt, int half) {
        const _Float16* s = pAsrc + ((size_t)half << 17) + ((size_t)kt << 6);
        char* d = smem + LDSA(slot) + (half << 14) + (w << 10);
        __builtin_amdgcn_global_load_lds((const __attribute__((address_space(1))) void*)s,
                                         (__attribute__((address_space(3))) void*)d, 16, 0, 0);
        __builtin_amdgcn_global_load_lds((const __attribute__((address_space(1))) void*)(s + (1 << 16)),
                                         (__attribute__((address_space(3))) void*)(d + 8192), 16, 0, 0);
    };
    auto stB = [&](int slot, int kt, int half) {
        const _Float16* s = pBsrc + ((size_t)half << 17) + ((size_t)kt << 6);
        char* d = smem + LDSB(slot) + (half << 14) + (w << 10);
        __builtin_amdgcn_global_load_lds((const __attribute__((address_space(1))) void*)s,
                                         (__attribute__((address_space(3))) void*)d, 16, 0, 0);
        __builtin_amdgcn_global_load_lds((const __attribute__((address_space(1))) void*)(s + (1 << 16)),
                                         (__attribute__((address_space(3))) void*)(d + 8192), 16, 0, 0);
    };

    // ---- swizzled LDS reads: physical 16B slot = logical slot ^ (row & 7)
    const int aRowB = ((wm << 7) + (l & 15)) << 7;            // row * 128 B
    const int bRowB = 65536 + (((wn << 6) + (l & 15)) << 7);
    const int xk0 = (((l >> 4) ^ (l & 7)) << 4);
    const int xk1 = ((((l >> 4) + 4) ^ (l & 7)) << 4);
    auto LDA = [&](int slot, int mi, int ks) -> f16x8 {
        return *(const f16x8*)(smem + (slot << 15) + aRowB + (mi << 11) + (ks ? xk1 : xk0));
    };
    auto LDB = [&](int slot, int ni, int ks) -> f16x8 {
        return *(const f16x8*)(smem + (slot << 15) + bRowB + (ni << 11) + (ks ? xk1 : xk0));
    };

    f32x4 acc[8][4] = {};
    f16x8 a[4][2], b[4][2];

    // ================= prologue: B(0), A(0), B(1); wait B(0)+A(0), leave B(1) in flight
    stB(0, 0, 0); stB(0, 0, 1);
    stA(0, 0, 0); stA(0, 0, 1);
    stB(1, 1, 0); stB(1, 1, 1);
    asm volatile("s_waitcnt vmcnt(2)" ::: "memory");
    __builtin_amdgcn_s_barrier();
    __builtin_amdgcn_sched_barrier(0);

    // ================= main loop: iters 0..6 compute K-tiles 2i, 2i+1
#pragma unroll 1
    for (int i = 0; i < 7; ++i) {
        const int u = 2 * i;
        // ---- PH0 (K-tile u, slot0, m0-3 x n0-1) | stage A(u+1) h0 -> slot1
#pragma unroll
        for (int mi = 0; mi < 4; ++mi) { a[mi][0] = LDA(0, mi, 0); a[mi][1] = LDA(0, mi, 1); }
#pragma unroll
        for (int ni = 0; ni < 2; ++ni) { b[ni][0] = LDB(0, ni, 0); b[ni][1] = LDB(0, ni, 1); }
        stA(1, u + 1, 0);
        __builtin_amdgcn_s_barrier();
        MFMA_Q(0, 0)
        __builtin_amdgcn_s_barrier();
        // ---- PH1 (m0-3 x n2-3) | stage A(u+1) h1
        b[2][0] = LDB(0, 2, 0); b[2][1] = LDB(0, 2, 1);
        b[3][0] = LDB(0, 3, 0); b[3][1] = LDB(0, 3, 1);
        stA(1, u + 1, 1);
        __builtin_amdgcn_s_barrier();
        MFMA_Q(0, 2)
        __builtin_amdgcn_s_barrier();
        // ---- PH2 (m4-7 x n0-1) | stage B(u+2) h0 -> slot0
#pragma unroll
        for (int mi = 0; mi < 4; ++mi) { a[mi][0] = LDA(0, mi + 4, 0); a[mi][1] = LDA(0, mi + 4, 1); }
        stB(0, u + 2, 0);
        __builtin_amdgcn_s_barrier();
        MFMA_Q(4, 0)
        __builtin_amdgcn_s_barrier();
        // ---- PH3 (m4-7 x n2-3) | stage B(u+2) h1; publish A(u+1),B(u+1)
        stB(0, u + 2, 1);
        asm volatile("s_waitcnt vmcnt(4)" ::: "memory");
        __builtin_amdgcn_s_barrier();
        __builtin_amdgcn_sched_barrier(0);
        MFMA_Q(4, 2)
        __builtin_amdgcn_s_barrier();
        // ---- PH4 (K-tile u+1, slot1, m0-3 x n0-1) | stage A(u+2) h0 -> slot0
#pragma unroll
        for (int mi = 0; mi < 4; ++mi) { a[mi][0] = LDA(1, mi, 0); a[mi][1] = LDA(1, mi, 1); }
#pragma unroll
        for (int ni = 0; ni < 2; ++ni) { b[ni][0] = LDB(1, ni, 0); b[ni][1] = LDB(1, ni, 1); }
        stA(0, u + 2, 0);
        __builtin_amdgcn_s_barrier();
        MFMA_Q(0, 0)
        __builtin_amdgcn_s_barrier();
        // ---- PH5 (m0-3 x n2-3) | stage A(u+2) h1
        b[2][0] = LDB(1, 2, 0); b[2][1] = LDB(1, 2, 1);
        b[3][0] = LDB(1, 3, 0); b[3][1] = LDB(1, 3, 1);
        stA(0, u + 2, 1);
        __builtin_amdgcn_s_barrier();
        MFMA_Q(0, 2)
        __builtin_amdgcn_s_barrier();
        // ---- PH6 (m4-7 x n0-1) | stage B(u+3) h0 -> slot1
#pragma unroll
        for (int mi = 0; mi < 4; ++mi) { a[mi][0] = LDA(1, mi + 4, 0); a[mi][1] = LDA(1, mi + 4, 1); }
        stB(1, u + 3, 0);
        __builtin_amdgcn_s_barrier();
        MFMA_Q(4, 0)
        __builtin_amdgcn_s_barrier();
        // ---- PH7 (m4-7 x n2-3) | stage B(u+3) h1; publish A(u+2),B(u+2)
        stB(1, u + 3, 1);
        asm volatile("s_waitcnt vmcnt(4)" ::: "memory");
        __builtin_amdgcn_s_barrier();
        __builtin_amdgcn_sched_barrier(0);
        MFMA_Q(4, 2)
        __builtin_amdgcn_s_barrier();
    }

    // ================= peeled last iteration (K-tiles 14, 15)
    {
        // PH0 | stage A(15) h0
#pragma unroll
        for (int mi = 0; mi < 4; ++mi) { a[mi][0] = LDA(0, mi, 0); a[mi][1] = LDA(0, mi, 1); }
#pragma unroll
        for (int ni = 0; ni < 2; ++ni) { b[ni][0] = LDB(0, ni, 0); b[ni][1] = LDB(0, ni, 1); }
        stA(1, 15, 0);
        __builtin_amdgcn_s_barrier();
        MFMA_Q(0, 0)
        __builtin_amdgcn_s_barrier();
        // PH1 | stage A(15) h1
        b[2][0] = LDB(0, 2, 0); b[2][1] = LDB(0, 2, 1);
        b[3][0] = LDB(0, 3, 0); b[3][1] = LDB(0, 3, 1);
        stA(1, 15, 1);
        __builtin_amdgcn_s_barrier();
        MFMA_Q(0, 2)
        __builtin_amdgcn_s_barrier();
        // PH2
#pragma unroll
        for (int mi = 0; mi < 4; ++mi) { a[mi][0] = LDA(0, mi + 4, 0); a[mi][1] = LDA(0, mi + 4, 1); }
        __builtin_amdgcn_s_barrier();
        MFMA_Q(4, 0)
        __builtin_amdgcn_s_barrier();
        // PH3 | drain everything (A(15),B(15) must land)
        asm volatile("s_waitcnt vmcnt(0)" ::: "memory");
        __builtin_amdgcn_s_barrier();
        __builtin_amdgcn_sched_barrier(0);
        MFMA_Q(4, 2)
        __builtin_amdgcn_s_barrier();
        // PH4-7: plain compute of K-tile 15 (slot1)
#pragma unroll
        for (int mi = 0; mi < 4; ++mi) { a[mi][0] = LDA(1, mi, 0); a[mi][1] = LDA(1, mi, 1); }
#pragma unroll
        for (int ni = 0; ni < 2; ++ni) { b[ni][0] = LDB(1, ni, 0); b[ni][1] = LDB(1, ni, 1); }
        __builtin_amdgcn_s_barrier();
        MFMA_Q(0, 0)
        __builtin_amdgcn_s_barrier();
        b[2][0] = LDB(1, 2, 0); b[2][1] = LDB(1, 2, 1);
        b[3][0] = LDB(1, 3, 0); b[3][1] = LDB(1, 3, 1);
        __builtin_amdgcn_s_barrier();
        MFMA_Q(0, 2)
        __builtin_amdgcn_s_barrier();
#pragma unroll
        for (int mi = 0; mi < 4; ++mi) { a[mi][0] = LDA(1, mi + 4, 0); a[mi][1] = LDA(1, mi + 4, 1); }
        __builtin_amdgcn_s_barrier();
        MFMA_Q(4, 0)
        MFMA_Q(4, 2)
    }

    // ================= epilogue: LDS bounce -> coalesced f16x8 stores.
    // Transposed acc: lane owns m-row = l&15, n-cols (wn*64 + ni*16 + (l>>4)*4 + j).
    __syncthreads();   // all waves done with LDS tiles; reuse smem as 256x256 f16
#pragma unroll
    for (int mi = 0; mi < 8; ++mi) {
        const int m = (wm << 7) + (mi << 4) + (l & 15);
        const int msw = m & 7;
#pragma unroll
        for (int ni = 0; ni < 4; ++ni) {
            const int n0 = (wn << 6) + (ni << 4) + ((l >> 4) << 2);
            const float4 bv4 = *(const float4*)&bias[bcol + n0];
            f16x4 h;
            h[0] = (_Float16)(acc[mi][ni][0] + bv4.x);
            h[1] = (_Float16)(acc[mi][ni][1] + bv4.y);
            h[2] = (_Float16)(acc[mi][ni][2] + bv4.z);
            h[3] = (_Float16)(acc[mi][ni][3] + bv4.w);
            const int c8 = n0 >> 2;                                   // 8-byte granule
            *(f16x4*)(smem + m * 512 + (((c8 >> 1) ^ msw) << 4) + ((c8 & 1) << 3)) = h;
        }
    }
    __syncthreads();
#pragma unroll
    for (int it = 0; it < 16; ++it) {
        const int row = (tid >> 5) + (it << 4);
        const int c16 = tid & 31;
        f16x8 vv = *(const f16x8*)(smem + row * 512 + ((c16 ^ (row & 7)) << 4));
        *(f16x8*)&Ch[(size_t)(brow + row) * NQKV + bcol + (c16 << 3)] = vv;
    }
}

// ---------------------------------------------------------------- per-position attention
__global__ __launch_bounds__(256) void attn_kernel(const _Float16* __restrict__ QKVh,
                                                   float* __restrict__ out) {
    __shared__ _Float16 vlds[4][1024];
    __shared__ float attlds[4][16][16];

    const int w = threadIdx.x >> 6, l = threadIdx.x & 63;
    const size_t p = (size_t)blockIdx.x * 4 + w;
    const _Float16* base = QKVh + p * NQKV;
    const _Float16* qrow = base;
    const _Float16* krow = base + 1024;
    const _Float16* vrow = base + 2048;
    const int h = l & 15;
    const int g4 = (l >> 4) * 4;

    *(uint4*)&vlds[w][l * 16]     = *(const uint4*)&vrow[l * 16];
    *(uint4*)&vlds[w][l * 16 + 8] = *(const uint4*)&vrow[l * 16 + 8];

    const int fo = (l & 15) * HDIM + (l >> 4) * 8;
    f16x8 aK0 = *(const f16x8*)&krow[fo];
    f16x8 aK1 = *(const f16x8*)&krow[fo + 32];
    f16x8 bQ0 = *(const f16x8*)&qrow[fo];
    f16x8 bQ1 = *(const f16x8*)&qrow[fo + 32];

    f32x4 sT = {0.f, 0.f, 0.f, 0.f};
    sT = __builtin_amdgcn_mfma_f32_16x16x32_f16(aK0, bQ0, sT, 0, 0, 0);
    sT = __builtin_amdgcn_mfma_f32_16x16x32_f16(aK1, bQ1, sT, 0, 0, 0);
    // lane holds s[h = l&15][g = g4 + i] = sT[i]

    float m = fmaxf(fmaxf(sT[0], sT[1]), fmaxf(sT[2], sT[3]));
    m = fmaxf(m, __shfl_xor(m, 16));
    m = fmaxf(m, __shfl_xor(m, 32));
    float e0 = __expf(sT[0] - m), e1 = __expf(sT[1] - m);
    float e2 = __expf(sT[2] - m), e3 = __expf(sT[3] - m);
    float s = e0 + e1 + e2 + e3;
    s += __shfl_xor(s, 16);
    s += __shfl_xor(s, 32);
    const float inv = 1.0f / s;

    float4 att = make_float4(e0 * inv, e1 * inv, e2 * inv, e3 * inv);
    *(float4*)&attlds[w][h][g4] = att;
    __syncthreads();

    const int dbase = (l >> 4) * 16;
    float acc[16];
#pragma unroll
    for (int c = 0; c < 16; ++c) acc[c] = 0.f;

#pragma unroll
    for (int g = 0; g < 16; ++g) {
        const float av = attlds[w][h][g];
        f16x8 v0 = *(const f16x8*)&vlds[w][g * HDIM + dbase];
        f16x8 v1 = *(const f16x8*)&vlds[w][g * HDIM + dbase + 8];
#pragma unroll
        for (int c = 0; c < 8; ++c) {
            acc[c]     += av * (float)v0[c];
            acc[c + 8] += av * (float)v1[c];
        }
    }

    float* op = out + p * DIM + h * HDIM + dbase;
#pragma unroll
    for (int c = 0; c < 16; c += 4)
        *(float4*)(op + c) = make_float4(acc[c], acc[c + 1], acc[c + 2], acc[c + 3]);
}

// ---------------------------------------------------------------- launch
extern "C" void kernel_launch(void* const* d_in, const int* in_sizes, int n_in,
                              void* d_out, int out_size, void* d_ws, size_t ws_size,
                              hipStream_t stream) {
    const float* x  = (const float*)d_in[0];
    const float* Wq = (const float*)d_in[1];
    const float* bq = (const float*)d_in[2];
    const float* Wk = (const float*)d_in[3];
    const float* bk = (const float*)d_in[4];
    const float* Wv = (const float*)d_in[5];
    const float* bv = (const float*)d_in[6];
    float* out = (float*)d_out;

    char* ws = (char*)d_ws;
    _Float16* Xh  = (_Float16*)ws;
    _Float16* Wth = (_Float16*)(ws + 134217728);
    float*    bias = (float*)(ws + 134217728 + 6291456);
    _Float16* Ch  = (_Float16*)(ws + 134217728 + 6291456 + 12288);

    // allow 128 KiB dynamic LDS (gfx950 has 160 KiB/CU)
    (void)hipFuncSetAttribute((const void*)qkv_gemm_kernel,
                              hipFuncAttributeMaxDynamicSharedMemorySize, 131072);

    hipLaunchKernelGGL(cvt_x_kernel, dim3(2048), dim3(256), 0, stream,
                       x, Xh, (M_TOTAL * DIM) / 4);
    hipLaunchKernelGGL(cvt_w_kernel, dim3(32, 32, 3), dim3(32, 32), 0, stream,
                       Wq, Wk, Wv, Wth);
    hipLaunchKernelGGL(bias_kernel, dim3(12), dim3(256), 0, stream,
                       bq, bk, bv, bias);
    hipLaunchKernelGGL(qkv_gemm_kernel, dim3((M_TOTAL / 256) * (NQKV / 256)), dim3(512), 131072, stream,
                       Xh, Wth, bias, Ch);
    hipLaunchKernelGGL(attn_kernel, dim3(M_TOTAL / 4), dim3(256), 0, stream,
                       Ch, out);
}